// Round 11
// baseline (128.394 us; speedup 1.0000x reference)
//
#include <hip/hip_runtime.h>
#include <hip/hip_fp16.h>
#include <math.h>

#define F_CNT 1024
#define H_IMG 192
#define W_IMG 192
#define HW (H_IMG * W_IMG)
#define EPSF 1e-8f
#define N_SEG 16
#define SEG_LEN 64               // 16 waves x 64 gaussians
#define PIX_PER_BLK 144          // 256 blocks x 144 px = 36864 exactly
#define LOG2E 1.4426950408889634f

// ws layout: F_CNT sorted records, 8 floats (32 B) each = 32 KB total.
//   a = (mx, my, LA, LB)   b = (LC, opv, h2(r,g), h2(b,0))
//   LA = 0.5*log2e*conA, LB = log2e*conB, LC = 0.5*log2e*conC
// alpha = min(opv * exp2(-(LA*dx^2 + LB*dx*dy + LC*dy^2)), 0.99)

// ---------------------------------------------------------------- kernel 1
// PROVEN single-block prep+sort — byte-identical to the R8 passing version.
// Do NOT restructure (5/5 restructuring attempts failed).
__global__ __launch_bounds__(1024)
void prep_sort_kernel(const float* __restrict__ vp,
                      const int*   __restrict__ faces,
                      const float* __restrict__ rot_qs,
                      const float* __restrict__ log_scales,
                      const float* __restrict__ colors,
                      const float* __restrict__ log_opac,
                      float* __restrict__ params,
                      float* __restrict__ out)
{
    __shared__ float sp[8][F_CNT];
    __shared__ float skey[F_CNT];
    __shared__ int   sidx[F_CNT];

    const int f = threadIdx.x;
    if (f == 0) out[3 * HW] = 0.0f;   // zero the loss accumulator slot

    const int ia = faces[3 * f + 0], ib = faces[3 * f + 1], ic = faces[3 * f + 2];
    const float Ax = vp[3 * ia + 0], Ay = vp[3 * ia + 1], Az = vp[3 * ia + 2];
    const float Bx = vp[3 * ib + 0], By = vp[3 * ib + 1], Bz = vp[3 * ib + 2];
    const float Cx = vp[3 * ic + 0], Cy = vp[3 * ic + 1], Cz = vp[3 * ic + 2];

    const float tx = (Ax + Bx + Cx) / 3.0f;
    const float ty = (Ay + By + Cy) / 3.0f;
    const float tz = (Az + Bz + Cz) / 3.0f;

    const float e1x = Bx - Ax, e1y = By - Ay, e1z = Bz - Az;
    const float e2x = Cx - Ax, e2y = Cy - Ay, e2z = Cz - Az;

    const float n1 = sqrtf(e1x * e1x + e1y * e1y + e1z * e1z) + EPSF;
    const float ux = e1x / n1, uy = e1y / n1, uz = e1z / n1;
    const float cnx = e1y * e2z - e1z * e2y;
    const float cny = e1z * e2x - e1x * e2z;
    const float cnz = e1x * e2y - e1y * e2x;
    const float n2 = sqrtf(cnx * cnx + cny * cny + cnz * cnz) + EPSF;
    const float wxv = cnx / n2, wyv = cny / n2, wzv = cnz / n2;
    const float vx = wyv * uz - wzv * uy;
    const float vy = wzv * ux - wxv * uz;
    const float vz = wxv * uy - wyv * ux;

    const float q0 = rot_qs[4 * f + 0], q1 = rot_qs[4 * f + 1];
    const float q2 = rot_qs[4 * f + 2], q3 = rot_qs[4 * f + 3];
    const float qn = sqrtf(q0 * q0 + q1 * q1 + q2 * q2 + q3 * q3) + EPSF;
    const float qw = q0 / qn, qx = q1 / qn, qy = q2 / qn, qz = q3 / qn;
    const float R00 = 1.0f - 2.0f * (qy * qy + qz * qz);
    const float R01 = 2.0f * (qx * qy - qw * qz);
    const float R02 = 2.0f * (qx * qz + qw * qy);
    const float R10 = 2.0f * (qx * qy + qw * qz);
    const float R11 = 1.0f - 2.0f * (qx * qx + qz * qz);
    const float R12 = 2.0f * (qy * qz - qw * qx);
    const float R20 = 2.0f * (qx * qz - qw * qy);
    const float R21 = 2.0f * (qy * qz + qw * qx);
    const float R22 = 1.0f - 2.0f * (qx * qx + qy * qy);

    const float s0 = expf(log_scales[3 * f + 0]);
    const float s1 = expf(log_scales[3 * f + 1]);
    const float s2 = expf(log_scales[3 * f + 2]);

    float G00, G10, G20, G01, G11, G21, G02, G12, G22;
    {
        float c0 = s0 * R00, c1 = s1 * R01, c2 = s2 * R02;
        G00 = ux * c0 + vx * c1 + wxv * c2;
        G10 = uy * c0 + vy * c1 + wyv * c2;
        G20 = uz * c0 + vz * c1 + wzv * c2;
    }
    {
        float c0 = s0 * R10, c1 = s1 * R11, c2 = s2 * R12;
        G01 = ux * c0 + vx * c1 + wxv * c2;
        G11 = uy * c0 + vy * c1 + wyv * c2;
        G21 = uz * c0 + vz * c1 + wzv * c2;
    }
    {
        float c0 = s0 * R20, c1 = s1 * R21, c2 = s2 * R22;
        G02 = ux * c0 + vx * c1 + wxv * c2;
        G12 = uy * c0 + vy * c1 + wyv * c2;
        G22 = uz * c0 + vz * c1 + wzv * c2;
    }

    const float gs0 = sqrtf(G00 * G00 + G10 * G10 + G20 * G20);
    const float gs1 = sqrtf(G01 * G01 + G11 * G11 + G21 * G21);
    const float gs2 = sqrtf(G02 * G02 + G12 * G12 + G22 * G22);
    const float d0 = gs0 + EPSF, d1 = gs1 + EPSF, d2 = gs2 + EPSF;
    const float r00 = G00 / d0, r10 = G10 / d0, r20 = G20 / d0;
    const float r01 = G01 / d1, r11 = G11 / d1, r21 = G21 / d1;
    const float r02 = G02 / d2, r12 = G12 / d2, r22 = G22 / d2;

    const float Qw = 0.5f * sqrtf(fmaxf(EPSF, 1.0f + r00 + r11 + r22));
    const float Qx = copysignf(0.5f * sqrtf(fmaxf(EPSF, 1.0f + r00 - r11 - r22)), r21 - r12);
    const float Qy = copysignf(0.5f * sqrtf(fmaxf(EPSF, 1.0f - r00 + r11 - r22)), r02 - r20);
    const float Qz = copysignf(0.5f * sqrtf(fmaxf(EPSF, 1.0f - r00 - r11 + r22)), r10 - r01);

    const float qn2 = sqrtf(Qw * Qw + Qx * Qx + Qy * Qy + Qz * Qz) + EPSF;
    const float pw = Qw / qn2, px = Qx / qn2, py = Qy / qn2, pz = Qz / qn2;
    const float N00 = 1.0f - 2.0f * (py * py + pz * pz);
    const float N01 = 2.0f * (px * py - pw * pz);
    const float N02 = 2.0f * (px * pz + pw * py);
    const float N10 = 2.0f * (px * py + pw * pz);
    const float N11 = 1.0f - 2.0f * (px * px + pz * pz);
    const float N12 = 2.0f * (py * pz - pw * px);
    const float N20 = 2.0f * (px * pz - pw * py);
    const float N21 = 2.0f * (py * pz + pw * px);
    const float N22 = 1.0f - 2.0f * (px * px + py * py);

    const float M00 = N00 * gs0, M01 = N01 * gs1, M02 = N02 * gs2;
    const float M10 = N10 * gs0, M11 = N11 * gs1, M12 = N12 * gs2;
    const float M20 = N20 * gs0, M21 = N21 * gs1, M22 = N22 * gs2;
    const float C00 = M00 * M00 + M01 * M01 + M02 * M02;
    const float C01 = M00 * M10 + M01 * M11 + M02 * M12;
    const float C02 = M00 * M20 + M01 * M21 + M02 * M22;
    const float C11 = M10 * M10 + M11 * M11 + M12 * M12;
    const float C12 = M10 * M20 + M11 * M21 + M12 * M22;
    const float C22 = M20 * M20 + M21 * M21 + M22 * M22;

    const float valid = (tz > 0.2f) ? 1.0f : 0.0f;
    const float Zc = fmaxf(tz, 0.2f);
    const float mx = 200.0f * tx / Zc + 96.0f;
    const float my = 200.0f * ty / Zc + 96.0f;
    const float j00 = 200.0f / Zc;
    const float j02 = -200.0f * tx / (Zc * Zc);
    const float j11 = 200.0f / Zc;
    const float j12 = -200.0f * ty / (Zc * Zc);
    const float v00 = j00 * j00 * C00 + 2.0f * j00 * j02 * C02 + j02 * j02 * C22 + 0.3f;
    const float v01 = j00 * j11 * C01 + j00 * j12 * C02 + j02 * j11 * C12 + j02 * j12 * C22;
    const float v11 = j11 * j11 * C11 + 2.0f * j11 * j12 * C12 + j12 * j12 * C22 + 0.3f;
    const float det = fmaxf(v00 * v11 - v01 * v01, EPSF);
    const float conA = v11 / det, conB = -v01 / det, conC = v00 / det;
    const float opv = expf(log_opac[f]) * valid;

    union { __half2 h; float f; } c01u, c2u;
    c01u.h = __floats2half2_rn(colors[3 * f + 0], colors[3 * f + 1]);
    c2u.h  = __floats2half2_rn(colors[3 * f + 2], 0.0f);

    sp[0][f] = mx;
    sp[1][f] = my;
    sp[2][f] = 0.5f * LOG2E * conA;   // LA
    sp[3][f] = LOG2E * conB;          // LB
    sp[4][f] = 0.5f * LOG2E * conC;   // LC
    sp[5][f] = opv;
    sp[6][f] = c01u.f;
    sp[7][f] = c2u.f;
    skey[f] = Zc;
    sidx[f] = f;

    // ---- bitonic sort on (Zc, idx): stable ascending argsort ----
    for (int k = 2; k <= F_CNT; k <<= 1) {
        for (int j = k >> 1; j > 0; j >>= 1) {
            __syncthreads();
            const int i = f;
            const int x = i ^ j;
            if (x > i) {
                float ki = skey[i], kx = skey[x];
                int   ii = sidx[i], ix = sidx[x];
                bool up = ((i & k) == 0);
                bool sw = up ? (ki > kx || (ki == kx && ii > ix))
                             : (ki < kx || (ki == kx && ii < ix));
                if (sw) {
                    skey[i] = kx; skey[x] = ki;
                    sidx[i] = ix; sidx[x] = ii;
                }
            }
        }
    }
    __syncthreads();

    // ---- gather-write sorted 32 B records ----
    const int src = sidx[f];
    float4* __restrict__ d4 = (float4*)params + 2 * f;
    d4[0] = make_float4(sp[0][src], sp[1][src], sp[2][src], sp[3][src]);
    d4[1] = make_float4(sp[4][src], sp[5][src], sp[6][src], sp[7][src]);
}

// ---------------------------------------------------------------- kernel 2
// 256 blocks x 144 px, 1024 threads = 16 waves; wave w composites
// depth-segment w (64 sorted records, contiguous in LDS, direct indexing,
// broadcast reads); each lane covers px slots {lane, lane+64, lane<16:
// lane+128}. 16 (C,T) partials fold front-to-back; bg telescopes.
__global__ __launch_bounds__(1024)
void render_kernel(const float* __restrict__ params,
                   const float* __restrict__ img,
                   const float* __restrict__ mask,
                   float* __restrict__ out)
{
    __shared__ float4 lds4[F_CNT * 2];   // 32 KB records; reused for fold
    __shared__ float4 spill[256];        // 4 KB fold overflow (2304-2048)
    __shared__ float  lossb[PIX_PER_BLK];

    const int tid  = threadIdx.x;
    const int lane = tid & 63;
    const int wv   = tid >> 6;           // 0..15

    // ---- stage all 1024 sorted records: contiguous, coalesced ----
    const float4* __restrict__ rec4 = (const float4*)params;
    lds4[tid]        = rec4[tid];
    lds4[1024 + tid] = rec4[1024 + tid];
    __syncthreads();

    const int pbase = blockIdx.x * PIX_PER_BLK;
    const int p0 = pbase + lane, p1 = p0 + 64, p2 = p0 + 128;
    const float fx0 = (float)(p0 % W_IMG), fy0 = (float)(p0 / W_IMG);
    const float fx1 = (float)(p1 % W_IMG), fy1 = (float)(p1 / W_IMG);
    const float fx2 = (float)(p2 % W_IMG), fy2 = (float)(p2 / W_IMG);

    float T0 = 1.0f, R0 = 0.0f, G0 = 0.0f, B0 = 0.0f;
    float T1 = 1.0f, R1 = 0.0f, G1 = 0.0f, B1 = 0.0f;
    float T2 = 1.0f, R2 = 0.0f, G2 = 0.0f, B2 = 0.0f;

    const float4* __restrict__ Lb = lds4 + (wv << 7);   // wv*64 records * 2
    #pragma unroll 4
    for (int i = 0; i < SEG_LEN; ++i) {
        const float4 a = Lb[2 * i + 0];   // mx, my, LA, LB (broadcast)
        const float4 b = Lb[2 * i + 1];   // LC, opv, h2(r,g), h2(b,0)
        union { float f; __half2 h; } urg, ub;
        urg.f = b.z;  ub.f = b.w;
        const float2 crg = __half22float2(urg.h);
        const float  cb  = __low2float(ub.h);

        {   // slot 0
            const float dx = fx0 - a.x, dy = fy0 - a.y;
            const float t  = fmaf(a.w, dy, a.z * dx);
            const float u2 = (b.x * dy) * dy;
            const float n  = -fmaf(t, dx, u2);
            const float e  = exp2f(fminf(n, 0.0f));
            const float al = fminf(b.y * e, 0.99f);
            const float w  = al * T0;
            R0 = fmaf(w, crg.x, R0); G0 = fmaf(w, crg.y, G0); B0 = fmaf(w, cb, B0);
            T0 -= w;
        }
        {   // slot 1
            const float dx = fx1 - a.x, dy = fy1 - a.y;
            const float t  = fmaf(a.w, dy, a.z * dx);
            const float u2 = (b.x * dy) * dy;
            const float n  = -fmaf(t, dx, u2);
            const float e  = exp2f(fminf(n, 0.0f));
            const float al = fminf(b.y * e, 0.99f);
            const float w  = al * T1;
            R1 = fmaf(w, crg.x, R1); G1 = fmaf(w, crg.y, G1); B1 = fmaf(w, cb, B1);
            T1 -= w;
        }
        {   // slot 2 (lanes >= 16 compute harmless extra math)
            const float dx = fx2 - a.x, dy = fy2 - a.y;
            const float t  = fmaf(a.w, dy, a.z * dx);
            const float u2 = (b.x * dy) * dy;
            const float n  = -fmaf(t, dx, u2);
            const float e  = exp2f(fminf(n, 0.0f));
            const float al = fminf(b.y * e, 0.99f);
            const float w  = al * T2;
            R2 = fmaf(w, crg.x, R2); G2 = fmaf(w, crg.y, G2); B2 = fmaf(w, cb, B2);
            T2 -= w;
        }
    }

    __syncthreads();                       // all waves done reading records

    // ---- fold partials: [16][144] float4 = 2304 entries; first 2048 reuse
    // lds4, last 256 in spill ----
    {
        const int i0 = wv * PIX_PER_BLK + lane;
        const float4 v0 = make_float4(R0, G0, B0, T0);
        if (i0 < 2048) lds4[i0] = v0; else spill[i0 - 2048] = v0;
        const int i1 = i0 + 64;
        const float4 v1 = make_float4(R1, G1, B1, T1);
        if (i1 < 2048) lds4[i1] = v1; else spill[i1 - 2048] = v1;
        if (lane < 16) {
            const int i2 = i0 + 128;
            const float4 v2 = make_float4(R2, G2, B2, T2);
            if (i2 < 2048) lds4[i2] = v2; else spill[i2 - 2048] = v2;
        }
    }
    __syncthreads();

    float lsum = 0.0f;
    if (tid < PIX_PER_BLK) {
        float R = 0.0f, G = 0.0f, B = 0.0f, Tt = 1.0f;
        #pragma unroll
        for (int s = 0; s < N_SEG; ++s) {
            const int idx = s * PIX_PER_BLK + tid;
            const float4 c = (idx < 2048) ? lds4[idx] : spill[idx - 2048];
            R += Tt * c.x; G += Tt * c.y; B += Tt * c.z;
            Tt *= c.w;
        }
        const float bg = Tt;               // sum(w) telescopes to 1 - T_total
        const float o0 = R + bg, o1 = G + bg, o2 = B + bg;
        const int p = pbase + tid;
        out[p]          = o0;
        out[HW + p]     = o1;
        out[2 * HW + p] = o2;

        const float m = mask[p];
        const float base = 1.0f - m;
        const float e0 = o0 - (base + img[p] * m);
        const float e1 = o1 - (base + img[HW + p] * m);
        const float e2 = o2 - (base + img[2 * HW + p] * m);
        lsum = e0 * e0 + e1 * e1 + e2 * e2;
    }

    if (tid < PIX_PER_BLK) lossb[tid] = lsum;
    __syncthreads();
    if (tid < 64) {
        float s = lossb[tid] + lossb[tid + 64] + (tid < 16 ? lossb[tid + 128] : 0.0f);
        #pragma unroll
        for (int off = 32; off > 0; off >>= 1) s += __shfl_down(s, off);
        if (tid == 0)
            atomicAdd(out + 3 * HW, s * (1.0f / (float)(3 * HW)));
    }
}

extern "C" void kernel_launch(void* const* d_in, const int* in_sizes, int n_in,
                              void* d_out, int out_size, void* d_ws, size_t ws_size,
                              hipStream_t stream)
{
    const float* img        = (const float*)d_in[0];
    const float* mask       = (const float*)d_in[1];
    const float* vp         = (const float*)d_in[2];
    const int*   faces      = (const int*)d_in[3];
    const float* rot_qs     = (const float*)d_in[4];
    const float* log_scales = (const float*)d_in[5];
    const float* colors     = (const float*)d_in[6];
    const float* log_opac   = (const float*)d_in[7];
    float* out    = (float*)d_out;
    float* params = (float*)d_ws;   // 32 KB used

    prep_sort_kernel<<<1, F_CNT, 0, stream>>>(vp, faces, rot_qs, log_scales,
                                              colors, log_opac, params, out);
    render_kernel<<<HW / PIX_PER_BLK, 1024, 0, stream>>>(params, img, mask, out);
}

// Round 12
// 127.303 us; speedup vs baseline: 1.0086x; 1.0086x over previous
//
#include <hip/hip_runtime.h>
#include <hip/hip_fp16.h>
#include <math.h>

#define F_CNT 1024
#define H_IMG 192
#define W_IMG 192
#define HW (H_IMG * W_IMG)
#define EPSF 1e-8f
#define N_SEG 8
#define SEG_LEN 128
#define HALF_PX 72               // two 72-px half-blocks per block
#define PIX_PER_BLK 144
#define LOG2E 1.4426950408889634f

// ws layout: F_CNT sorted records, 8 floats (32 B) each = 32 KB.
//   a = (mx, my, LA, LB)   b = (LC, opv, h2(r,g), h2(b,0))
//   LA = 0.5*log2e*conA, LB = log2e*conB, LC = 0.5*log2e*conC
// alpha = min(opv * exp2(-(LA*dx^2 + LB*dx*dy + LC*dy^2)), 0.99)
// min over dx of the exponent = dy^2*(LC - LB^2/(4LA));
// skip iff (4*LA*LC - LB^2)*dymin^2 > 140*LA  (exact, division-free).

// ---------------------------------------------------------------- kernel 1
// PROVEN single-block prep+sort — byte-identical to R8/R11 passing version.
__global__ __launch_bounds__(1024)
void prep_sort_kernel(const float* __restrict__ vp,
                      const int*   __restrict__ faces,
                      const float* __restrict__ rot_qs,
                      const float* __restrict__ log_scales,
                      const float* __restrict__ colors,
                      const float* __restrict__ log_opac,
                      float* __restrict__ params,
                      float* __restrict__ out)
{
    __shared__ float sp[8][F_CNT];
    __shared__ float skey[F_CNT];
    __shared__ int   sidx[F_CNT];

    const int f = threadIdx.x;
    if (f == 0) out[3 * HW] = 0.0f;   // zero the loss accumulator slot

    const int ia = faces[3 * f + 0], ib = faces[3 * f + 1], ic = faces[3 * f + 2];
    const float Ax = vp[3 * ia + 0], Ay = vp[3 * ia + 1], Az = vp[3 * ia + 2];
    const float Bx = vp[3 * ib + 0], By = vp[3 * ib + 1], Bz = vp[3 * ib + 2];
    const float Cx = vp[3 * ic + 0], Cy = vp[3 * ic + 1], Cz = vp[3 * ic + 2];

    const float tx = (Ax + Bx + Cx) / 3.0f;
    const float ty = (Ay + By + Cy) / 3.0f;
    const float tz = (Az + Bz + Cz) / 3.0f;

    const float e1x = Bx - Ax, e1y = By - Ay, e1z = Bz - Az;
    const float e2x = Cx - Ax, e2y = Cy - Ay, e2z = Cz - Az;

    const float n1 = sqrtf(e1x * e1x + e1y * e1y + e1z * e1z) + EPSF;
    const float ux = e1x / n1, uy = e1y / n1, uz = e1z / n1;
    const float cnx = e1y * e2z - e1z * e2y;
    const float cny = e1z * e2x - e1x * e2z;
    const float cnz = e1x * e2y - e1y * e2x;
    const float n2 = sqrtf(cnx * cnx + cny * cny + cnz * cnz) + EPSF;
    const float wxv = cnx / n2, wyv = cny / n2, wzv = cnz / n2;
    const float vx = wyv * uz - wzv * uy;
    const float vy = wzv * ux - wxv * uz;
    const float vz = wxv * uy - wyv * ux;

    const float q0 = rot_qs[4 * f + 0], q1 = rot_qs[4 * f + 1];
    const float q2 = rot_qs[4 * f + 2], q3 = rot_qs[4 * f + 3];
    const float qn = sqrtf(q0 * q0 + q1 * q1 + q2 * q2 + q3 * q3) + EPSF;
    const float qw = q0 / qn, qx = q1 / qn, qy = q2 / qn, qz = q3 / qn;
    const float R00 = 1.0f - 2.0f * (qy * qy + qz * qz);
    const float R01 = 2.0f * (qx * qy - qw * qz);
    const float R02 = 2.0f * (qx * qz + qw * qy);
    const float R10 = 2.0f * (qx * qy + qw * qz);
    const float R11 = 1.0f - 2.0f * (qx * qx + qz * qz);
    const float R12 = 2.0f * (qy * qz - qw * qx);
    const float R20 = 2.0f * (qx * qz - qw * qy);
    const float R21 = 2.0f * (qy * qz + qw * qx);
    const float R22 = 1.0f - 2.0f * (qx * qx + qy * qy);

    const float s0 = expf(log_scales[3 * f + 0]);
    const float s1 = expf(log_scales[3 * f + 1]);
    const float s2 = expf(log_scales[3 * f + 2]);

    float G00, G10, G20, G01, G11, G21, G02, G12, G22;
    {
        float c0 = s0 * R00, c1 = s1 * R01, c2 = s2 * R02;
        G00 = ux * c0 + vx * c1 + wxv * c2;
        G10 = uy * c0 + vy * c1 + wyv * c2;
        G20 = uz * c0 + vz * c1 + wzv * c2;
    }
    {
        float c0 = s0 * R10, c1 = s1 * R11, c2 = s2 * R12;
        G01 = ux * c0 + vx * c1 + wxv * c2;
        G11 = uy * c0 + vy * c1 + wyv * c2;
        G21 = uz * c0 + vz * c1 + wzv * c2;
    }
    {
        float c0 = s0 * R20, c1 = s1 * R21, c2 = s2 * R22;
        G02 = ux * c0 + vx * c1 + wxv * c2;
        G12 = uy * c0 + vy * c1 + wyv * c2;
        G22 = uz * c0 + vz * c1 + wzv * c2;
    }

    const float gs0 = sqrtf(G00 * G00 + G10 * G10 + G20 * G20);
    const float gs1 = sqrtf(G01 * G01 + G11 * G11 + G21 * G21);
    const float gs2 = sqrtf(G02 * G02 + G12 * G12 + G22 * G22);
    const float d0 = gs0 + EPSF, d1 = gs1 + EPSF, d2 = gs2 + EPSF;
    const float r00 = G00 / d0, r10 = G10 / d0, r20 = G20 / d0;
    const float r01 = G01 / d1, r11 = G11 / d1, r21 = G21 / d1;
    const float r02 = G02 / d2, r12 = G12 / d2, r22 = G22 / d2;

    const float Qw = 0.5f * sqrtf(fmaxf(EPSF, 1.0f + r00 + r11 + r22));
    const float Qx = copysignf(0.5f * sqrtf(fmaxf(EPSF, 1.0f + r00 - r11 - r22)), r21 - r12);
    const float Qy = copysignf(0.5f * sqrtf(fmaxf(EPSF, 1.0f - r00 + r11 - r22)), r02 - r20);
    const float Qz = copysignf(0.5f * sqrtf(fmaxf(EPSF, 1.0f - r00 - r11 + r22)), r10 - r01);

    const float qn2 = sqrtf(Qw * Qw + Qx * Qx + Qy * Qy + Qz * Qz) + EPSF;
    const float pw = Qw / qn2, px = Qx / qn2, py = Qy / qn2, pz = Qz / qn2;
    const float N00 = 1.0f - 2.0f * (py * py + pz * pz);
    const float N01 = 2.0f * (px * py - pw * pz);
    const float N02 = 2.0f * (px * pz + pw * py);
    const float N10 = 2.0f * (px * py + pw * pz);
    const float N11 = 1.0f - 2.0f * (px * px + pz * pz);
    const float N12 = 2.0f * (py * pz - pw * px);
    const float N20 = 2.0f * (px * pz - pw * py);
    const float N21 = 2.0f * (py * pz + pw * px);
    const float N22 = 1.0f - 2.0f * (px * px + py * py);

    const float M00 = N00 * gs0, M01 = N01 * gs1, M02 = N02 * gs2;
    const float M10 = N10 * gs0, M11 = N11 * gs1, M12 = N12 * gs2;
    const float M20 = N20 * gs0, M21 = N21 * gs1, M22 = N22 * gs2;
    const float C00 = M00 * M00 + M01 * M01 + M02 * M02;
    const float C01 = M00 * M10 + M01 * M11 + M02 * M12;
    const float C02 = M00 * M20 + M01 * M21 + M02 * M22;
    const float C11 = M10 * M10 + M11 * M11 + M12 * M12;
    const float C12 = M10 * M20 + M11 * M21 + M12 * M22;
    const float C22 = M20 * M20 + M21 * M21 + M22 * M22;

    const float valid = (tz > 0.2f) ? 1.0f : 0.0f;
    const float Zc = fmaxf(tz, 0.2f);
    const float mx = 200.0f * tx / Zc + 96.0f;
    const float my = 200.0f * ty / Zc + 96.0f;
    const float j00 = 200.0f / Zc;
    const float j02 = -200.0f * tx / (Zc * Zc);
    const float j11 = 200.0f / Zc;
    const float j12 = -200.0f * ty / (Zc * Zc);
    const float v00 = j00 * j00 * C00 + 2.0f * j00 * j02 * C02 + j02 * j02 * C22 + 0.3f;
    const float v01 = j00 * j11 * C01 + j00 * j12 * C02 + j02 * j11 * C12 + j02 * j12 * C22;
    const float v11 = j11 * j11 * C11 + 2.0f * j11 * j12 * C12 + j12 * j12 * C22 + 0.3f;
    const float det = fmaxf(v00 * v11 - v01 * v01, EPSF);
    const float conA = v11 / det, conB = -v01 / det, conC = v00 / det;
    const float opv = expf(log_opac[f]) * valid;

    union { __half2 h; float f; } c01u, c2u;
    c01u.h = __floats2half2_rn(colors[3 * f + 0], colors[3 * f + 1]);
    c2u.h  = __floats2half2_rn(colors[3 * f + 2], 0.0f);

    sp[0][f] = mx;
    sp[1][f] = my;
    sp[2][f] = 0.5f * LOG2E * conA;   // LA
    sp[3][f] = LOG2E * conB;          // LB
    sp[4][f] = 0.5f * LOG2E * conC;   // LC
    sp[5][f] = opv;
    sp[6][f] = c01u.f;
    sp[7][f] = c2u.f;
    skey[f] = Zc;
    sidx[f] = f;

    // ---- bitonic sort on (Zc, idx): stable ascending argsort ----
    for (int k = 2; k <= F_CNT; k <<= 1) {
        for (int j = k >> 1; j > 0; j >>= 1) {
            __syncthreads();
            const int i = f;
            const int x = i ^ j;
            if (x > i) {
                float ki = skey[i], kx = skey[x];
                int   ii = sidx[i], ix = sidx[x];
                bool up = ((i & k) == 0);
                bool sw = up ? (ki > kx || (ki == kx && ii > ix))
                             : (ki < kx || (ki == kx && ii < ix));
                if (sw) {
                    skey[i] = kx; skey[x] = ki;
                    sidx[i] = ix; sidx[x] = ii;
                }
            }
        }
    }
    __syncthreads();

    // ---- gather-write sorted 32 B records ----
    const int src = sidx[f];
    float4* __restrict__ d4 = (float4*)params + 2 * f;
    d4[0] = make_float4(sp[0][src], sp[1][src], sp[2][src], sp[3][src]);
    d4[1] = make_float4(sp[4][src], sp[5][src], sp[6][src], sp[7][src]);
}

// ---------------------------------------------------------------- kernel 2
// 256 blocks x (72 px at b*72  +  72 px at 18432 + b*72): anti-correlated
// halves balance per-CU load. 512 threads = 8 waves x 128-gaussian depth
// segments (contiguous LDS, direct indexing, broadcast reads). Per gaussian
// per half: wave-uniform y-cull branch (exact, division-free, keep-biased;
// skipped alpha < 3e-11). Order preserved exactly. Fold front-to-back.
__global__ __launch_bounds__(512)
void render_kernel(const float* __restrict__ params,
                   const float* __restrict__ img,
                   const float* __restrict__ mask,
                   float* __restrict__ out)
{
    __shared__ float4 lds4[F_CNT * 2];   // 32 KB records; reused for fold
    __shared__ float  lossb[PIX_PER_BLK];

    const int tid  = threadIdx.x;
    const int lane = tid & 63;
    const int wv   = tid >> 6;

    // ---- stage all 1024 sorted records: contiguous, coalesced ----
    const float4* __restrict__ rec4 = (const float4*)params;
    #pragma unroll
    for (int k = 0; k < 4; ++k)
        lds4[k * 512 + tid] = rec4[k * 512 + tid];
    __syncthreads();

    const int b   = blockIdx.x;
    const int pb1 = b * HALF_PX;              // half 1 base
    const int pb2 = HW / 2 + b * HALF_PX;     // half 2 base (other image half)

    // row bands of each half (<= 2 rows each)
    const float r1a = (float)(pb1 / W_IMG);
    const float r1b = (float)((pb1 + HALF_PX - 1) / W_IMG);
    const float r2a = (float)(pb2 / W_IMG);
    const float r2b = (float)((pb2 + HALF_PX - 1) / W_IMG);

    // slot pixels: s0 = pb1+lane, s1 = pb1+64+lane (lane<8),
    //              s2 = pb2+lane, s3 = pb2+64+lane (lane<8)
    const int p0 = pb1 + lane,      p1 = pb1 + 64 + lane;
    const int p2 = pb2 + lane,      p3 = pb2 + 64 + lane;
    const float fx0 = (float)(p0 % W_IMG), fy0 = (float)(p0 / W_IMG);
    const float fx1 = (float)(p1 % W_IMG), fy1 = (float)(p1 / W_IMG);
    const float fx2 = (float)(p2 % W_IMG), fy2 = (float)(p2 / W_IMG);
    const float fx3 = (float)(p3 % W_IMG), fy3 = (float)(p3 / W_IMG);

    float T0 = 1.0f, R0 = 0.0f, G0 = 0.0f, B0 = 0.0f;
    float T1 = 1.0f, R1 = 0.0f, G1 = 0.0f, B1 = 0.0f;
    float T2 = 1.0f, R2 = 0.0f, G2 = 0.0f, B2 = 0.0f;
    float T3 = 1.0f, R3 = 0.0f, G3 = 0.0f, B3 = 0.0f;

    const float4* __restrict__ Lb = lds4 + (wv << 8);   // wv*128 records * 2
    for (int i = 0; i < SEG_LEN; ++i) {
        const float4 a  = Lb[2 * i + 0];   // mx, my, LA, LB (broadcast)
        const float4 bb = Lb[2 * i + 1];   // LC, opv, h2(r,g), h2(b,0)
        const float LA = a.z, LB = a.w, LC = bb.x, my = a.y;

        // exact min-exponent test, division-free, lane-uniform:
        // skip half iff (4*LA*LC - LB*LB) * dymin^2 > 140*LA
        const float t4  = fmaf(-LB, LB, 4.0f * LA * LC);
        const float thr = 140.0f * LA;
        const float dm1 = fmaxf(0.0f, fmaxf(r1a - my, my - r1b));
        const float dm2 = fmaxf(0.0f, fmaxf(r2a - my, my - r2b));
        const bool hit1 = (t4 * dm1) * dm1 <= thr;
        const bool hit2 = (t4 * dm2) * dm2 <= thr;

        if (hit1 || hit2) {
            union { float f; __half2 h; } urg, ub;
            urg.f = bb.z;  ub.f = bb.w;
            const float2 crg = __half22float2(urg.h);
            const float  cb  = __low2float(ub.h);

            if (hit1) {
                {   // slot 0
                    const float dx = fx0 - a.x, dy = fy0 - my;
                    const float t  = fmaf(LB, dy, LA * dx);
                    const float u2 = (LC * dy) * dy;
                    const float n  = -fmaf(t, dx, u2);
                    const float e  = exp2f(fminf(n, 0.0f));
                    const float al = fminf(bb.y * e, 0.99f);
                    const float w  = al * T0;
                    R0 = fmaf(w, crg.x, R0); G0 = fmaf(w, crg.y, G0); B0 = fmaf(w, cb, B0);
                    T0 -= w;
                }
                {   // slot 1 (only lanes < 8 are real pixels)
                    const float dx = fx1 - a.x, dy = fy1 - my;
                    const float t  = fmaf(LB, dy, LA * dx);
                    const float u2 = (LC * dy) * dy;
                    const float n  = -fmaf(t, dx, u2);
                    const float e  = exp2f(fminf(n, 0.0f));
                    const float al = fminf(bb.y * e, 0.99f);
                    const float w  = al * T1;
                    R1 = fmaf(w, crg.x, R1); G1 = fmaf(w, crg.y, G1); B1 = fmaf(w, cb, B1);
                    T1 -= w;
                }
            }
            if (hit2) {
                {   // slot 2
                    const float dx = fx2 - a.x, dy = fy2 - my;
                    const float t  = fmaf(LB, dy, LA * dx);
                    const float u2 = (LC * dy) * dy;
                    const float n  = -fmaf(t, dx, u2);
                    const float e  = exp2f(fminf(n, 0.0f));
                    const float al = fminf(bb.y * e, 0.99f);
                    const float w  = al * T2;
                    R2 = fmaf(w, crg.x, R2); G2 = fmaf(w, crg.y, G2); B2 = fmaf(w, cb, B2);
                    T2 -= w;
                }
                {   // slot 3 (only lanes < 8 are real pixels)
                    const float dx = fx3 - a.x, dy = fy3 - my;
                    const float t  = fmaf(LB, dy, LA * dx);
                    const float u2 = (LC * dy) * dy;
                    const float n  = -fmaf(t, dx, u2);
                    const float e  = exp2f(fminf(n, 0.0f));
                    const float al = fminf(bb.y * e, 0.99f);
                    const float w  = al * T3;
                    R3 = fmaf(w, crg.x, R3); G3 = fmaf(w, crg.y, G3); B3 = fmaf(w, cb, B3);
                    T3 -= w;
                }
            }
        }
    }

    __syncthreads();                       // all waves done reading records
    // fold partials: [8][144] local px: q<72 -> half1 (pb1+q), else half2
    float4* __restrict__ fold4 = lds4;
    fold4[wv * PIX_PER_BLK + lane] = make_float4(R0, G0, B0, T0);
    if (lane < 8)
        fold4[wv * PIX_PER_BLK + 64 + lane] = make_float4(R1, G1, B1, T1);
    fold4[wv * PIX_PER_BLK + 72 + lane] = make_float4(R2, G2, B2, T2);
    if (lane < 8)
        fold4[wv * PIX_PER_BLK + 136 + lane] = make_float4(R3, G3, B3, T3);
    __syncthreads();

    float lsum = 0.0f;
    if (tid < PIX_PER_BLK) {
        float R = 0.0f, G = 0.0f, B = 0.0f, Tt = 1.0f;
        #pragma unroll
        for (int s = 0; s < N_SEG; ++s) {
            const float4 c = fold4[s * PIX_PER_BLK + tid];
            R += Tt * c.x; G += Tt * c.y; B += Tt * c.z;
            Tt *= c.w;
        }
        const float bg = Tt;               // sum(w) telescopes to 1 - T_total
        const float o0 = R + bg, o1 = G + bg, o2 = B + bg;
        const int p = (tid < HALF_PX) ? (pb1 + tid) : (pb2 + tid - HALF_PX);
        out[p]          = o0;
        out[HW + p]     = o1;
        out[2 * HW + p] = o2;

        const float m = mask[p];
        const float base = 1.0f - m;
        const float e0 = o0 - (base + img[p] * m);
        const float e1 = o1 - (base + img[HW + p] * m);
        const float e2 = o2 - (base + img[2 * HW + p] * m);
        lsum = e0 * e0 + e1 * e1 + e2 * e2;
    }

    if (tid < PIX_PER_BLK) lossb[tid] = lsum;
    __syncthreads();
    if (tid < 64) {
        float s = lossb[tid] + lossb[tid + 64] + (tid < 16 ? lossb[tid + 128] : 0.0f);
        #pragma unroll
        for (int off = 32; off > 0; off >>= 1) s += __shfl_down(s, off);
        if (tid == 0)
            atomicAdd(out + 3 * HW, s * (1.0f / (float)(3 * HW)));
    }
}

extern "C" void kernel_launch(void* const* d_in, const int* in_sizes, int n_in,
                              void* d_out, int out_size, void* d_ws, size_t ws_size,
                              hipStream_t stream)
{
    const float* img        = (const float*)d_in[0];
    const float* mask       = (const float*)d_in[1];
    const float* vp         = (const float*)d_in[2];
    const int*   faces      = (const int*)d_in[3];
    const float* rot_qs     = (const float*)d_in[4];
    const float* log_scales = (const float*)d_in[5];
    const float* colors     = (const float*)d_in[6];
    const float* log_opac   = (const float*)d_in[7];
    float* out    = (float*)d_out;
    float* params = (float*)d_ws;   // 32 KB used

    prep_sort_kernel<<<1, F_CNT, 0, stream>>>(vp, faces, rot_qs, log_scales,
                                              colors, log_opac, params, out);
    render_kernel<<<(HW / 2) / HALF_PX, 512, 0, stream>>>(params, img, mask, out);
}

// Round 13
// 125.264 us; speedup vs baseline: 1.0250x; 1.0163x over previous
//
#include <hip/hip_runtime.h>
#include <hip/hip_fp16.h>
#include <math.h>

#define F_CNT 1024
#define H_IMG 192
#define W_IMG 192
#define HW (H_IMG * W_IMG)
#define EPSF 1e-8f
#define N_SEG 8
#define SEG_LEN 128
#define HALF_PX 72               // two 72-px half-blocks per block
#define PIX_PER_BLK 144
#define LOG2E 1.4426950408889634f

#define RCP(x) __builtin_amdgcn_rcpf(x)   // v_rcp_f32, ~1 ulp, smooth paths only

// ws layout: F_CNT sorted records, 8 floats (32 B) each = 32 KB.
//   a = (mx, my, LA, LB)   b = (LC, opv, h2(r,g), h2(b,0))
//   LA = 0.5*log2e*conA, LB = log2e*conB, LC = 0.5*log2e*conC
// alpha = min(opv * exp2(-(LA*dx^2 + LB*dx*dy + LC*dy^2)), 0.99)

// ---------------------------------------------------------------- kernel 1
// PROVEN single-block prep+sort shape. Data path identical to R8/R11/R12:
// same math expressions (divisions -> v_rcp on smooth paths only; the
// tz/Zc sort-key chain is bit-identical), same comparator, same LDS layout.
// Only sync granularity changed: phases with j<32 are intra-wave (partners
// within one 64-aligned chunk; predecessor j=32 phase also intra-wave), so
// hardware barriers are elided there (wave lockstep; compiler pinned by
// wave_barrier). 15 s_barriers instead of 55.
__global__ __launch_bounds__(1024)
void prep_sort_kernel(const float* __restrict__ vp,
                      const int*   __restrict__ faces,
                      const float* __restrict__ rot_qs,
                      const float* __restrict__ log_scales,
                      const float* __restrict__ colors,
                      const float* __restrict__ log_opac,
                      float* __restrict__ params,
                      float* __restrict__ out)
{
    __shared__ float sp[8][F_CNT];
    __shared__ float skey[F_CNT];
    __shared__ int   sidx[F_CNT];

    const int f = threadIdx.x;
    if (f == 0) out[3 * HW] = 0.0f;   // zero the loss accumulator slot

    const int ia = faces[3 * f + 0], ib = faces[3 * f + 1], ic = faces[3 * f + 2];
    const float Ax = vp[3 * ia + 0], Ay = vp[3 * ia + 1], Az = vp[3 * ia + 2];
    const float Bx = vp[3 * ib + 0], By = vp[3 * ib + 1], Bz = vp[3 * ib + 2];
    const float Cx = vp[3 * ic + 0], Cy = vp[3 * ic + 1], Cz = vp[3 * ic + 2];

    // ---- sort-key chain: EXACT IEEE (do not touch) ----
    const float tx = (Ax + Bx + Cx) / 3.0f;
    const float ty = (Ay + By + Cy) / 3.0f;
    const float tz = (Az + Bz + Cz) / 3.0f;

    const float e1x = Bx - Ax, e1y = By - Ay, e1z = Bz - Az;
    const float e2x = Cx - Ax, e2y = Cy - Ay, e2z = Cz - Az;

    const float rn1 = RCP(sqrtf(e1x * e1x + e1y * e1y + e1z * e1z) + EPSF);
    const float ux = e1x * rn1, uy = e1y * rn1, uz = e1z * rn1;
    const float cnx = e1y * e2z - e1z * e2y;
    const float cny = e1z * e2x - e1x * e2z;
    const float cnz = e1x * e2y - e1y * e2x;
    const float rn2 = RCP(sqrtf(cnx * cnx + cny * cny + cnz * cnz) + EPSF);
    const float wxv = cnx * rn2, wyv = cny * rn2, wzv = cnz * rn2;
    const float vx = wyv * uz - wzv * uy;
    const float vy = wzv * ux - wxv * uz;
    const float vz = wxv * uy - wyv * ux;

    const float q0 = rot_qs[4 * f + 0], q1 = rot_qs[4 * f + 1];
    const float q2 = rot_qs[4 * f + 2], q3 = rot_qs[4 * f + 3];
    const float rqn = RCP(sqrtf(q0 * q0 + q1 * q1 + q2 * q2 + q3 * q3) + EPSF);
    const float qw = q0 * rqn, qx = q1 * rqn, qy = q2 * rqn, qz = q3 * rqn;
    const float R00 = 1.0f - 2.0f * (qy * qy + qz * qz);
    const float R01 = 2.0f * (qx * qy - qw * qz);
    const float R02 = 2.0f * (qx * qz + qw * qy);
    const float R10 = 2.0f * (qx * qy + qw * qz);
    const float R11 = 1.0f - 2.0f * (qx * qx + qz * qz);
    const float R12 = 2.0f * (qy * qz - qw * qx);
    const float R20 = 2.0f * (qx * qz - qw * qy);
    const float R21 = 2.0f * (qy * qz + qw * qx);
    const float R22 = 1.0f - 2.0f * (qx * qx + qy * qy);

    const float s0 = expf(log_scales[3 * f + 0]);
    const float s1 = expf(log_scales[3 * f + 1]);
    const float s2 = expf(log_scales[3 * f + 2]);

    float G00, G10, G20, G01, G11, G21, G02, G12, G22;
    {
        float c0 = s0 * R00, c1 = s1 * R01, c2 = s2 * R02;
        G00 = ux * c0 + vx * c1 + wxv * c2;
        G10 = uy * c0 + vy * c1 + wyv * c2;
        G20 = uz * c0 + vz * c1 + wzv * c2;
    }
    {
        float c0 = s0 * R10, c1 = s1 * R11, c2 = s2 * R12;
        G01 = ux * c0 + vx * c1 + wxv * c2;
        G11 = uy * c0 + vy * c1 + wyv * c2;
        G21 = uz * c0 + vz * c1 + wzv * c2;
    }
    {
        float c0 = s0 * R20, c1 = s1 * R21, c2 = s2 * R22;
        G02 = ux * c0 + vx * c1 + wxv * c2;
        G12 = uy * c0 + vy * c1 + wyv * c2;
        G22 = uz * c0 + vz * c1 + wzv * c2;
    }

    const float gs0 = sqrtf(G00 * G00 + G10 * G10 + G20 * G20);
    const float gs1 = sqrtf(G01 * G01 + G11 * G11 + G21 * G21);
    const float gs2 = sqrtf(G02 * G02 + G12 * G12 + G22 * G22);
    const float rd0 = RCP(gs0 + EPSF), rd1 = RCP(gs1 + EPSF), rd2 = RCP(gs2 + EPSF);
    const float r00 = G00 * rd0, r10 = G10 * rd0, r20 = G20 * rd0;
    const float r01 = G01 * rd1, r11 = G11 * rd1, r21 = G21 * rd1;
    const float r02 = G02 * rd2, r12 = G12 * rd2, r22 = G22 * rd2;

    const float Qw = 0.5f * sqrtf(fmaxf(EPSF, 1.0f + r00 + r11 + r22));
    const float Qx = copysignf(0.5f * sqrtf(fmaxf(EPSF, 1.0f + r00 - r11 - r22)), r21 - r12);
    const float Qy = copysignf(0.5f * sqrtf(fmaxf(EPSF, 1.0f - r00 + r11 - r22)), r02 - r20);
    const float Qz = copysignf(0.5f * sqrtf(fmaxf(EPSF, 1.0f - r00 - r11 + r22)), r10 - r01);

    const float rqn2 = RCP(sqrtf(Qw * Qw + Qx * Qx + Qy * Qy + Qz * Qz) + EPSF);
    const float pw = Qw * rqn2, px = Qx * rqn2, py = Qy * rqn2, pz = Qz * rqn2;
    const float N00 = 1.0f - 2.0f * (py * py + pz * pz);
    const float N01 = 2.0f * (px * py - pw * pz);
    const float N02 = 2.0f * (px * pz + pw * py);
    const float N10 = 2.0f * (px * py + pw * pz);
    const float N11 = 1.0f - 2.0f * (px * px + pz * pz);
    const float N12 = 2.0f * (py * pz - pw * px);
    const float N20 = 2.0f * (px * pz - pw * py);
    const float N21 = 2.0f * (py * pz + pw * px);
    const float N22 = 1.0f - 2.0f * (px * px + py * py);

    const float M00 = N00 * gs0, M01 = N01 * gs1, M02 = N02 * gs2;
    const float M10 = N10 * gs0, M11 = N11 * gs1, M12 = N12 * gs2;
    const float M20 = N20 * gs0, M21 = N21 * gs1, M22 = N22 * gs2;
    const float C00 = M00 * M00 + M01 * M01 + M02 * M02;
    const float C01 = M00 * M10 + M01 * M11 + M02 * M12;
    const float C02 = M00 * M20 + M01 * M21 + M02 * M22;
    const float C11 = M10 * M10 + M11 * M11 + M12 * M12;
    const float C12 = M10 * M20 + M11 * M21 + M12 * M22;
    const float C22 = M20 * M20 + M21 * M21 + M22 * M22;

    const float valid = (tz > 0.2f) ? 1.0f : 0.0f;
    const float Zc = fmaxf(tz, 0.2f);           // sort key: exact
    const float rZc = RCP(Zc);
    const float mx = 200.0f * tx * rZc + 96.0f;
    const float my = 200.0f * ty * rZc + 96.0f;
    const float j00 = 200.0f * rZc;
    const float j02 = -200.0f * tx * (rZc * rZc);
    const float j11 = 200.0f * rZc;
    const float j12 = -200.0f * ty * (rZc * rZc);
    const float v00 = j00 * j00 * C00 + 2.0f * j00 * j02 * C02 + j02 * j02 * C22 + 0.3f;
    const float v01 = j00 * j11 * C01 + j00 * j12 * C02 + j02 * j11 * C12 + j02 * j12 * C22;
    const float v11 = j11 * j11 * C11 + 2.0f * j11 * j12 * C12 + j12 * j12 * C22 + 0.3f;
    const float rdet = RCP(fmaxf(v00 * v11 - v01 * v01, EPSF));
    const float conA = v11 * rdet, conB = -v01 * rdet, conC = v00 * rdet;
    const float opv = expf(log_opac[f]) * valid;

    union { __half2 h; float f; } c01u, c2u;
    c01u.h = __floats2half2_rn(colors[3 * f + 0], colors[3 * f + 1]);
    c2u.h  = __floats2half2_rn(colors[3 * f + 2], 0.0f);

    sp[0][f] = mx;
    sp[1][f] = my;
    sp[2][f] = 0.5f * LOG2E * conA;   // LA
    sp[3][f] = LOG2E * conB;          // LB
    sp[4][f] = 0.5f * LOG2E * conC;   // LC
    sp[5][f] = opv;
    sp[6][f] = c01u.f;
    sp[7][f] = c2u.f;
    skey[f] = Zc;
    sidx[f] = f;

    // ---- bitonic sort on (Zc, idx): stable ascending argsort.
    // Phases with j<32: partners within one 64-aligned wave chunk AND the
    // preceding j=32 phase is also intra-wave -> lockstep makes the
    // hardware barrier redundant (wave_barrier pins compiler ordering).
    for (int k = 2; k <= F_CNT; k <<= 1) {
        for (int j = k >> 1; j > 0; j >>= 1) {
            if (j >= 32) __syncthreads();
            else         __builtin_amdgcn_wave_barrier();
            const int i = f;
            const int x = i ^ j;
            if (x > i) {
                float ki = skey[i], kx = skey[x];
                int   ii = sidx[i], ix = sidx[x];
                bool up = ((i & k) == 0);
                bool sw = up ? (ki > kx || (ki == kx && ii > ix))
                             : (ki < kx || (ki == kx && ii < ix));
                if (sw) {
                    skey[i] = kx; skey[x] = ki;
                    sidx[i] = ix; sidx[x] = ii;
                }
            }
        }
    }
    __syncthreads();

    // ---- gather-write sorted 32 B records ----
    const int src = sidx[f];
    float4* __restrict__ d4 = (float4*)params + 2 * f;
    d4[0] = make_float4(sp[0][src], sp[1][src], sp[2][src], sp[3][src]);
    d4[1] = make_float4(sp[4][src], sp[5][src], sp[6][src], sp[7][src]);
}

// ---------------------------------------------------------------- kernel 2
// VERBATIM R12 render (passed): 256 blocks x (72 px at b*72 + 72 px at
// 18432 + b*72), 8 waves x 128-gaussian depth segments, wave-uniform
// y-cull, fold front-to-back, fused loss.
__global__ __launch_bounds__(512)
void render_kernel(const float* __restrict__ params,
                   const float* __restrict__ img,
                   const float* __restrict__ mask,
                   float* __restrict__ out)
{
    __shared__ float4 lds4[F_CNT * 2];   // 32 KB records; reused for fold
    __shared__ float  lossb[PIX_PER_BLK];

    const int tid  = threadIdx.x;
    const int lane = tid & 63;
    const int wv   = tid >> 6;

    const float4* __restrict__ rec4 = (const float4*)params;
    #pragma unroll
    for (int k = 0; k < 4; ++k)
        lds4[k * 512 + tid] = rec4[k * 512 + tid];
    __syncthreads();

    const int b   = blockIdx.x;
    const int pb1 = b * HALF_PX;
    const int pb2 = HW / 2 + b * HALF_PX;

    const float r1a = (float)(pb1 / W_IMG);
    const float r1b = (float)((pb1 + HALF_PX - 1) / W_IMG);
    const float r2a = (float)(pb2 / W_IMG);
    const float r2b = (float)((pb2 + HALF_PX - 1) / W_IMG);

    const int p0 = pb1 + lane,      p1 = pb1 + 64 + lane;
    const int p2 = pb2 + lane,      p3 = pb2 + 64 + lane;
    const float fx0 = (float)(p0 % W_IMG), fy0 = (float)(p0 / W_IMG);
    const float fx1 = (float)(p1 % W_IMG), fy1 = (float)(p1 / W_IMG);
    const float fx2 = (float)(p2 % W_IMG), fy2 = (float)(p2 / W_IMG);
    const float fx3 = (float)(p3 % W_IMG), fy3 = (float)(p3 / W_IMG);

    float T0 = 1.0f, R0 = 0.0f, G0 = 0.0f, B0 = 0.0f;
    float T1 = 1.0f, R1 = 0.0f, G1 = 0.0f, B1 = 0.0f;
    float T2 = 1.0f, R2 = 0.0f, G2 = 0.0f, B2 = 0.0f;
    float T3 = 1.0f, R3 = 0.0f, G3 = 0.0f, B3 = 0.0f;

    const float4* __restrict__ Lb = lds4 + (wv << 8);
    for (int i = 0; i < SEG_LEN; ++i) {
        const float4 a  = Lb[2 * i + 0];
        const float4 bb = Lb[2 * i + 1];
        const float LA = a.z, LB = a.w, LC = bb.x, my = a.y;

        const float t4  = fmaf(-LB, LB, 4.0f * LA * LC);
        const float thr = 140.0f * LA;
        const float dm1 = fmaxf(0.0f, fmaxf(r1a - my, my - r1b));
        const float dm2 = fmaxf(0.0f, fmaxf(r2a - my, my - r2b));
        const bool hit1 = (t4 * dm1) * dm1 <= thr;
        const bool hit2 = (t4 * dm2) * dm2 <= thr;

        if (hit1 || hit2) {
            union { float f; __half2 h; } urg, ub;
            urg.f = bb.z;  ub.f = bb.w;
            const float2 crg = __half22float2(urg.h);
            const float  cb  = __low2float(ub.h);

            if (hit1) {
                {
                    const float dx = fx0 - a.x, dy = fy0 - my;
                    const float t  = fmaf(LB, dy, LA * dx);
                    const float u2 = (LC * dy) * dy;
                    const float n  = -fmaf(t, dx, u2);
                    const float e  = exp2f(fminf(n, 0.0f));
                    const float al = fminf(bb.y * e, 0.99f);
                    const float w  = al * T0;
                    R0 = fmaf(w, crg.x, R0); G0 = fmaf(w, crg.y, G0); B0 = fmaf(w, cb, B0);
                    T0 -= w;
                }
                {
                    const float dx = fx1 - a.x, dy = fy1 - my;
                    const float t  = fmaf(LB, dy, LA * dx);
                    const float u2 = (LC * dy) * dy;
                    const float n  = -fmaf(t, dx, u2);
                    const float e  = exp2f(fminf(n, 0.0f));
                    const float al = fminf(bb.y * e, 0.99f);
                    const float w  = al * T1;
                    R1 = fmaf(w, crg.x, R1); G1 = fmaf(w, crg.y, G1); B1 = fmaf(w, cb, B1);
                    T1 -= w;
                }
            }
            if (hit2) {
                {
                    const float dx = fx2 - a.x, dy = fy2 - my;
                    const float t  = fmaf(LB, dy, LA * dx);
                    const float u2 = (LC * dy) * dy;
                    const float n  = -fmaf(t, dx, u2);
                    const float e  = exp2f(fminf(n, 0.0f));
                    const float al = fminf(bb.y * e, 0.99f);
                    const float w  = al * T2;
                    R2 = fmaf(w, crg.x, R2); G2 = fmaf(w, crg.y, G2); B2 = fmaf(w, cb, B2);
                    T2 -= w;
                }
                {
                    const float dx = fx3 - a.x, dy = fy3 - my;
                    const float t  = fmaf(LB, dy, LA * dx);
                    const float u2 = (LC * dy) * dy;
                    const float n  = -fmaf(t, dx, u2);
                    const float e  = exp2f(fminf(n, 0.0f));
                    const float al = fminf(bb.y * e, 0.99f);
                    const float w  = al * T3;
                    R3 = fmaf(w, crg.x, R3); G3 = fmaf(w, crg.y, G3); B3 = fmaf(w, cb, B3);
                    T3 -= w;
                }
            }
        }
    }

    __syncthreads();
    float4* __restrict__ fold4 = lds4;
    fold4[wv * PIX_PER_BLK + lane] = make_float4(R0, G0, B0, T0);
    if (lane < 8)
        fold4[wv * PIX_PER_BLK + 64 + lane] = make_float4(R1, G1, B1, T1);
    fold4[wv * PIX_PER_BLK + 72 + lane] = make_float4(R2, G2, B2, T2);
    if (lane < 8)
        fold4[wv * PIX_PER_BLK + 136 + lane] = make_float4(R3, G3, B3, T3);
    __syncthreads();

    float lsum = 0.0f;
    if (tid < PIX_PER_BLK) {
        float R = 0.0f, G = 0.0f, B = 0.0f, Tt = 1.0f;
        #pragma unroll
        for (int s = 0; s < N_SEG; ++s) {
            const float4 c = fold4[s * PIX_PER_BLK + tid];
            R += Tt * c.x; G += Tt * c.y; B += Tt * c.z;
            Tt *= c.w;
        }
        const float bg = Tt;
        const float o0 = R + bg, o1 = G + bg, o2 = B + bg;
        const int p = (tid < HALF_PX) ? (pb1 + tid) : (pb2 + tid - HALF_PX);
        out[p]          = o0;
        out[HW + p]     = o1;
        out[2 * HW + p] = o2;

        const float m = mask[p];
        const float base = 1.0f - m;
        const float e0 = o0 - (base + img[p] * m);
        const float e1 = o1 - (base + img[HW + p] * m);
        const float e2 = o2 - (base + img[2 * HW + p] * m);
        lsum = e0 * e0 + e1 * e1 + e2 * e2;
    }

    if (tid < PIX_PER_BLK) lossb[tid] = lsum;
    __syncthreads();
    if (tid < 64) {
        float s = lossb[tid] + lossb[tid + 64] + (tid < 16 ? lossb[tid + 128] : 0.0f);
        #pragma unroll
        for (int off = 32; off > 0; off >>= 1) s += __shfl_down(s, off);
        if (tid == 0)
            atomicAdd(out + 3 * HW, s * (1.0f / (float)(3 * HW)));
    }
}

extern "C" void kernel_launch(void* const* d_in, const int* in_sizes, int n_in,
                              void* d_out, int out_size, void* d_ws, size_t ws_size,
                              hipStream_t stream)
{
    const float* img        = (const float*)d_in[0];
    const float* mask       = (const float*)d_in[1];
    const float* vp         = (const float*)d_in[2];
    const int*   faces      = (const int*)d_in[3];
    const float* rot_qs     = (const float*)d_in[4];
    const float* log_scales = (const float*)d_in[5];
    const float* colors     = (const float*)d_in[6];
    const float* log_opac   = (const float*)d_in[7];
    float* out    = (float*)d_out;
    float* params = (float*)d_ws;   // 32 KB used

    prep_sort_kernel<<<1, F_CNT, 0, stream>>>(vp, faces, rot_qs, log_scales,
                                              colors, log_opac, params, out);
    render_kernel<<<(HW / 2) / HALF_PX, 512, 0, stream>>>(params, img, mask, out);
}

// Round 14
// 124.364 us; speedup vs baseline: 1.0324x; 1.0072x over previous
//
#include <hip/hip_runtime.h>
#include <hip/hip_fp16.h>
#include <math.h>

#define F_CNT 1024
#define H_IMG 192
#define W_IMG 192
#define HW (H_IMG * W_IMG)
#define EPSF 1e-8f
#define N_SEG 8
#define SEG_LEN 128
#define HALF_PX 72               // two 72-px half-blocks per block
#define PIX_PER_BLK 144
#define LOG2E 1.4426950408889634f

#define RCP(x) __builtin_amdgcn_rcpf(x)   // v_rcp_f32, ~1 ulp, smooth paths only

// ws layout: F_CNT sorted records, 8 floats (32 B) each = 32 KB.
//   a = (mx, my, reach2, LA)   b = (LB, LC, h2(r,g), h2(b,opv))
//   LA = 0.5*log2e*conA, LB = log2e*conB, LC = 0.5*log2e*conC
//   reach2 = 140*LA / (4*LA*LC - LB^2): skip a pixel-row band iff
//   dymin^2 > reach2  (exactly R12's division-free min-exponent>35 test).
// alpha = min(opv * exp2(-(LA*dx^2 + LB*dx*dy + LC*dy^2)), 0.99)

// ---------------------------------------------------------------- kernel 1
// PROVEN single-block prep+sort shape (R13 passing version); only the
// record field packing changed (proven-safe category: R6/R8/R13).
__global__ __launch_bounds__(1024)
void prep_sort_kernel(const float* __restrict__ vp,
                      const int*   __restrict__ faces,
                      const float* __restrict__ rot_qs,
                      const float* __restrict__ log_scales,
                      const float* __restrict__ colors,
                      const float* __restrict__ log_opac,
                      float* __restrict__ params,
                      float* __restrict__ out)
{
    __shared__ float sp[8][F_CNT];
    __shared__ float skey[F_CNT];
    __shared__ int   sidx[F_CNT];

    const int f = threadIdx.x;
    if (f == 0) out[3 * HW] = 0.0f;   // zero the loss accumulator slot

    const int ia = faces[3 * f + 0], ib = faces[3 * f + 1], ic = faces[3 * f + 2];
    const float Ax = vp[3 * ia + 0], Ay = vp[3 * ia + 1], Az = vp[3 * ia + 2];
    const float Bx = vp[3 * ib + 0], By = vp[3 * ib + 1], Bz = vp[3 * ib + 2];
    const float Cx = vp[3 * ic + 0], Cy = vp[3 * ic + 1], Cz = vp[3 * ic + 2];

    // ---- sort-key chain: EXACT IEEE (do not touch) ----
    const float tx = (Ax + Bx + Cx) / 3.0f;
    const float ty = (Ay + By + Cy) / 3.0f;
    const float tz = (Az + Bz + Cz) / 3.0f;

    const float e1x = Bx - Ax, e1y = By - Ay, e1z = Bz - Az;
    const float e2x = Cx - Ax, e2y = Cy - Ay, e2z = Cz - Az;

    const float rn1 = RCP(sqrtf(e1x * e1x + e1y * e1y + e1z * e1z) + EPSF);
    const float ux = e1x * rn1, uy = e1y * rn1, uz = e1z * rn1;
    const float cnx = e1y * e2z - e1z * e2y;
    const float cny = e1z * e2x - e1x * e2z;
    const float cnz = e1x * e2y - e1y * e2x;
    const float rn2 = RCP(sqrtf(cnx * cnx + cny * cny + cnz * cnz) + EPSF);
    const float wxv = cnx * rn2, wyv = cny * rn2, wzv = cnz * rn2;
    const float vx = wyv * uz - wzv * uy;
    const float vy = wzv * ux - wxv * uz;
    const float vz = wxv * uy - wyv * ux;

    const float q0 = rot_qs[4 * f + 0], q1 = rot_qs[4 * f + 1];
    const float q2 = rot_qs[4 * f + 2], q3 = rot_qs[4 * f + 3];
    const float rqn = RCP(sqrtf(q0 * q0 + q1 * q1 + q2 * q2 + q3 * q3) + EPSF);
    const float qw = q0 * rqn, qx = q1 * rqn, qy = q2 * rqn, qz = q3 * rqn;
    const float R00 = 1.0f - 2.0f * (qy * qy + qz * qz);
    const float R01 = 2.0f * (qx * qy - qw * qz);
    const float R02 = 2.0f * (qx * qz + qw * qy);
    const float R10 = 2.0f * (qx * qy + qw * qz);
    const float R11 = 1.0f - 2.0f * (qx * qx + qz * qz);
    const float R12 = 2.0f * (qy * qz - qw * qx);
    const float R20 = 2.0f * (qx * qz - qw * qy);
    const float R21 = 2.0f * (qy * qz + qw * qx);
    const float R22 = 1.0f - 2.0f * (qx * qx + qy * qy);

    const float s0 = expf(log_scales[3 * f + 0]);
    const float s1 = expf(log_scales[3 * f + 1]);
    const float s2 = expf(log_scales[3 * f + 2]);

    float G00, G10, G20, G01, G11, G21, G02, G12, G22;
    {
        float c0 = s0 * R00, c1 = s1 * R01, c2 = s2 * R02;
        G00 = ux * c0 + vx * c1 + wxv * c2;
        G10 = uy * c0 + vy * c1 + wyv * c2;
        G20 = uz * c0 + vz * c1 + wzv * c2;
    }
    {
        float c0 = s0 * R10, c1 = s1 * R11, c2 = s2 * R12;
        G01 = ux * c0 + vx * c1 + wxv * c2;
        G11 = uy * c0 + vy * c1 + wyv * c2;
        G21 = uz * c0 + vz * c1 + wzv * c2;
    }
    {
        float c0 = s0 * R20, c1 = s1 * R21, c2 = s2 * R22;
        G02 = ux * c0 + vx * c1 + wxv * c2;
        G12 = uy * c0 + vy * c1 + wyv * c2;
        G22 = uz * c0 + vz * c1 + wzv * c2;
    }

    const float gs0 = sqrtf(G00 * G00 + G10 * G10 + G20 * G20);
    const float gs1 = sqrtf(G01 * G01 + G11 * G11 + G21 * G21);
    const float gs2 = sqrtf(G02 * G02 + G12 * G12 + G22 * G22);
    const float rd0 = RCP(gs0 + EPSF), rd1 = RCP(gs1 + EPSF), rd2 = RCP(gs2 + EPSF);
    const float r00 = G00 * rd0, r10 = G10 * rd0, r20 = G20 * rd0;
    const float r01 = G01 * rd1, r11 = G11 * rd1, r21 = G21 * rd1;
    const float r02 = G02 * rd2, r12 = G12 * rd2, r22 = G22 * rd2;

    const float Qw = 0.5f * sqrtf(fmaxf(EPSF, 1.0f + r00 + r11 + r22));
    const float Qx = copysignf(0.5f * sqrtf(fmaxf(EPSF, 1.0f + r00 - r11 - r22)), r21 - r12);
    const float Qy = copysignf(0.5f * sqrtf(fmaxf(EPSF, 1.0f - r00 + r11 - r22)), r02 - r20);
    const float Qz = copysignf(0.5f * sqrtf(fmaxf(EPSF, 1.0f - r00 - r11 + r22)), r10 - r01);

    const float rqn2 = RCP(sqrtf(Qw * Qw + Qx * Qx + Qy * Qy + Qz * Qz) + EPSF);
    const float pw = Qw * rqn2, px = Qx * rqn2, py = Qy * rqn2, pz = Qz * rqn2;
    const float N00 = 1.0f - 2.0f * (py * py + pz * pz);
    const float N01 = 2.0f * (px * py - pw * pz);
    const float N02 = 2.0f * (px * pz + pw * py);
    const float N10 = 2.0f * (px * py + pw * pz);
    const float N11 = 1.0f - 2.0f * (px * px + pz * pz);
    const float N12 = 2.0f * (py * pz - pw * px);
    const float N20 = 2.0f * (px * pz - pw * py);
    const float N21 = 2.0f * (py * pz + pw * px);
    const float N22 = 1.0f - 2.0f * (px * px + py * py);

    const float M00 = N00 * gs0, M01 = N01 * gs1, M02 = N02 * gs2;
    const float M10 = N10 * gs0, M11 = N11 * gs1, M12 = N12 * gs2;
    const float M20 = N20 * gs0, M21 = N21 * gs1, M22 = N22 * gs2;
    const float C00 = M00 * M00 + M01 * M01 + M02 * M02;
    const float C01 = M00 * M10 + M01 * M11 + M02 * M12;
    const float C02 = M00 * M20 + M01 * M21 + M02 * M22;
    const float C11 = M10 * M10 + M11 * M11 + M12 * M12;
    const float C12 = M10 * M20 + M11 * M21 + M12 * M22;
    const float C22 = M20 * M20 + M21 * M21 + M22 * M22;

    const float valid = (tz > 0.2f) ? 1.0f : 0.0f;
    const float Zc = fmaxf(tz, 0.2f);           // sort key: exact
    const float rZc = RCP(Zc);
    const float mx = 200.0f * tx * rZc + 96.0f;
    const float my = 200.0f * ty * rZc + 96.0f;
    const float j00 = 200.0f * rZc;
    const float j02 = -200.0f * tx * (rZc * rZc);
    const float j11 = 200.0f * rZc;
    const float j12 = -200.0f * ty * (rZc * rZc);
    const float v00 = j00 * j00 * C00 + 2.0f * j00 * j02 * C02 + j02 * j02 * C22 + 0.3f;
    const float v01 = j00 * j11 * C01 + j00 * j12 * C02 + j02 * j11 * C12 + j02 * j12 * C22;
    const float v11 = j11 * j11 * C11 + 2.0f * j11 * j12 * C12 + j12 * j12 * C22 + 0.3f;
    const float rdet = RCP(fmaxf(v00 * v11 - v01 * v01, EPSF));
    const float conA = v11 * rdet, conB = -v01 * rdet, conC = v00 * rdet;
    const float opv = expf(log_opac[f]) * valid;

    const float LA = 0.5f * LOG2E * conA;
    const float LB = LOG2E * conB;
    const float LC = 0.5f * LOG2E * conC;
    const float t4 = fmaf(-LB, LB, 4.0f * LA * LC);   // > 0 (pos-def + 0.3 reg)
    const float reach2 = 140.0f * LA * RCP(fmaxf(t4, 1e-30f));

    union { __half2 h; float f; } c01u, cbo;
    c01u.h = __floats2half2_rn(colors[3 * f + 0], colors[3 * f + 1]);
    cbo.h  = __floats2half2_rn(colors[3 * f + 2], opv);

    sp[0][f] = mx;
    sp[1][f] = my;
    sp[2][f] = reach2;
    sp[3][f] = LA;
    sp[4][f] = LB;
    sp[5][f] = LC;
    sp[6][f] = c01u.f;
    sp[7][f] = cbo.f;
    skey[f] = Zc;
    sidx[f] = f;

    // ---- bitonic sort on (Zc, idx): stable ascending argsort.
    // Barriers only where a cross-wave write precedes (j>=32); intra-wave
    // phases rely on wave lockstep (wave_barrier pins compiler ordering).
    for (int k = 2; k <= F_CNT; k <<= 1) {
        for (int j = k >> 1; j > 0; j >>= 1) {
            if (j >= 32) __syncthreads();
            else         __builtin_amdgcn_wave_barrier();
            const int i = f;
            const int x = i ^ j;
            if (x > i) {
                float ki = skey[i], kx = skey[x];
                int   ii = sidx[i], ix = sidx[x];
                bool up = ((i & k) == 0);
                bool sw = up ? (ki > kx || (ki == kx && ii > ix))
                             : (ki < kx || (ki == kx && ii < ix));
                if (sw) {
                    skey[i] = kx; skey[x] = ki;
                    sidx[i] = ix; sidx[x] = ii;
                }
            }
        }
    }
    __syncthreads();

    // ---- gather-write sorted 32 B records ----
    const int src = sidx[f];
    float4* __restrict__ d4 = (float4*)params + 2 * f;
    d4[0] = make_float4(sp[0][src], sp[1][src], sp[2][src], sp[3][src]);
    d4[1] = make_float4(sp[4][src], sp[5][src], sp[6][src], sp[7][src]);
}

// ---------------------------------------------------------------- kernel 2
// R12's passing structure; only change: the cull test reads record-a alone
// (reach2 precomputed), record-b is loaded inside the hit branch — miss
// cost = 1 ds_read_b128 + ~6 VALU instead of 2 reads + full body.
__global__ __launch_bounds__(512)
void render_kernel(const float* __restrict__ params,
                   const float* __restrict__ img,
                   const float* __restrict__ mask,
                   float* __restrict__ out)
{
    __shared__ float4 lds4[F_CNT * 2];   // 32 KB records; reused for fold
    __shared__ float  lossb[PIX_PER_BLK];

    const int tid  = threadIdx.x;
    const int lane = tid & 63;
    const int wv   = tid >> 6;

    const float4* __restrict__ rec4 = (const float4*)params;
    #pragma unroll
    for (int k = 0; k < 4; ++k)
        lds4[k * 512 + tid] = rec4[k * 512 + tid];
    __syncthreads();

    const int b   = blockIdx.x;
    const int pb1 = b * HALF_PX;
    const int pb2 = HW / 2 + b * HALF_PX;

    const float r1a = (float)(pb1 / W_IMG);
    const float r1b = (float)((pb1 + HALF_PX - 1) / W_IMG);
    const float r2a = (float)(pb2 / W_IMG);
    const float r2b = (float)((pb2 + HALF_PX - 1) / W_IMG);

    const int p0 = pb1 + lane,      p1 = pb1 + 64 + lane;
    const int p2 = pb2 + lane,      p3 = pb2 + 64 + lane;
    const float fx0 = (float)(p0 % W_IMG), fy0 = (float)(p0 / W_IMG);
    const float fx1 = (float)(p1 % W_IMG), fy1 = (float)(p1 / W_IMG);
    const float fx2 = (float)(p2 % W_IMG), fy2 = (float)(p2 / W_IMG);
    const float fx3 = (float)(p3 % W_IMG), fy3 = (float)(p3 / W_IMG);

    float T0 = 1.0f, R0 = 0.0f, G0 = 0.0f, B0 = 0.0f;
    float T1 = 1.0f, R1 = 0.0f, G1 = 0.0f, B1 = 0.0f;
    float T2 = 1.0f, R2 = 0.0f, G2 = 0.0f, B2 = 0.0f;
    float T3 = 1.0f, R3 = 0.0f, G3 = 0.0f, B3 = 0.0f;

    const float4* __restrict__ Lb = lds4 + (wv << 8);
    for (int i = 0; i < SEG_LEN; ++i) {
        const float4 a = Lb[2 * i + 0];    // mx, my, reach2, LA (broadcast)
        const float my = a.y, reach2 = a.z;

        const float dm1 = fmaxf(0.0f, fmaxf(r1a - my, my - r1b));
        const float dm2 = fmaxf(0.0f, fmaxf(r2a - my, my - r2b));
        const bool hit1 = dm1 * dm1 <= reach2;
        const bool hit2 = dm2 * dm2 <= reach2;

        if (hit1 || hit2) {
            const float4 bb = Lb[2 * i + 1];   // LB, LC, h2(r,g), h2(b,opv)
            const float LA = a.w, LB = bb.x, LC = bb.y;
            union { float f; __half2 h; } urg, ubo;
            urg.f = bb.z;  ubo.f = bb.w;
            const float2 crg = __half22float2(urg.h);
            const float2 cbo = __half22float2(ubo.h);  // x = b, y = opv
            const float  cb  = cbo.x, opv = cbo.y;

            if (hit1) {
                {
                    const float dx = fx0 - a.x, dy = fy0 - my;
                    const float t  = fmaf(LB, dy, LA * dx);
                    const float u2 = (LC * dy) * dy;
                    const float n  = -fmaf(t, dx, u2);
                    const float e  = exp2f(fminf(n, 0.0f));
                    const float al = fminf(opv * e, 0.99f);
                    const float w  = al * T0;
                    R0 = fmaf(w, crg.x, R0); G0 = fmaf(w, crg.y, G0); B0 = fmaf(w, cb, B0);
                    T0 -= w;
                }
                {
                    const float dx = fx1 - a.x, dy = fy1 - my;
                    const float t  = fmaf(LB, dy, LA * dx);
                    const float u2 = (LC * dy) * dy;
                    const float n  = -fmaf(t, dx, u2);
                    const float e  = exp2f(fminf(n, 0.0f));
                    const float al = fminf(opv * e, 0.99f);
                    const float w  = al * T1;
                    R1 = fmaf(w, crg.x, R1); G1 = fmaf(w, crg.y, G1); B1 = fmaf(w, cb, B1);
                    T1 -= w;
                }
            }
            if (hit2) {
                {
                    const float dx = fx2 - a.x, dy = fy2 - my;
                    const float t  = fmaf(LB, dy, LA * dx);
                    const float u2 = (LC * dy) * dy;
                    const float n  = -fmaf(t, dx, u2);
                    const float e  = exp2f(fminf(n, 0.0f));
                    const float al = fminf(opv * e, 0.99f);
                    const float w  = al * T2;
                    R2 = fmaf(w, crg.x, R2); G2 = fmaf(w, crg.y, G2); B2 = fmaf(w, cb, B2);
                    T2 -= w;
                }
                {
                    const float dx = fx3 - a.x, dy = fy3 - my;
                    const float t  = fmaf(LB, dy, LA * dx);
                    const float u2 = (LC * dy) * dy;
                    const float n  = -fmaf(t, dx, u2);
                    const float e  = exp2f(fminf(n, 0.0f));
                    const float al = fminf(opv * e, 0.99f);
                    const float w  = al * T3;
                    R3 = fmaf(w, crg.x, R3); G3 = fmaf(w, crg.y, G3); B3 = fmaf(w, cb, B3);
                    T3 -= w;
                }
            }
        }
    }

    __syncthreads();
    float4* __restrict__ fold4 = lds4;
    fold4[wv * PIX_PER_BLK + lane] = make_float4(R0, G0, B0, T0);
    if (lane < 8)
        fold4[wv * PIX_PER_BLK + 64 + lane] = make_float4(R1, G1, B1, T1);
    fold4[wv * PIX_PER_BLK + 72 + lane] = make_float4(R2, G2, B2, T2);
    if (lane < 8)
        fold4[wv * PIX_PER_BLK + 136 + lane] = make_float4(R3, G3, B3, T3);
    __syncthreads();

    float lsum = 0.0f;
    if (tid < PIX_PER_BLK) {
        float R = 0.0f, G = 0.0f, B = 0.0f, Tt = 1.0f;
        #pragma unroll
        for (int s = 0; s < N_SEG; ++s) {
            const float4 c = fold4[s * PIX_PER_BLK + tid];
            R += Tt * c.x; G += Tt * c.y; B += Tt * c.z;
            Tt *= c.w;
        }
        const float bg = Tt;
        const float o0 = R + bg, o1 = G + bg, o2 = B + bg;
        const int p = (tid < HALF_PX) ? (pb1 + tid) : (pb2 + tid - HALF_PX);
        out[p]          = o0;
        out[HW + p]     = o1;
        out[2 * HW + p] = o2;

        const float m = mask[p];
        const float base = 1.0f - m;
        const float e0 = o0 - (base + img[p] * m);
        const float e1 = o1 - (base + img[HW + p] * m);
        const float e2 = o2 - (base + img[2 * HW + p] * m);
        lsum = e0 * e0 + e1 * e1 + e2 * e2;
    }

    if (tid < PIX_PER_BLK) lossb[tid] = lsum;
    __syncthreads();
    if (tid < 64) {
        float s = lossb[tid] + lossb[tid + 64] + (tid < 16 ? lossb[tid + 128] : 0.0f);
        #pragma unroll
        for (int off = 32; off > 0; off >>= 1) s += __shfl_down(s, off);
        if (tid == 0)
            atomicAdd(out + 3 * HW, s * (1.0f / (float)(3 * HW)));
    }
}

extern "C" void kernel_launch(void* const* d_in, const int* in_sizes, int n_in,
                              void* d_out, int out_size, void* d_ws, size_t ws_size,
                              hipStream_t stream)
{
    const float* img        = (const float*)d_in[0];
    const float* mask       = (const float*)d_in[1];
    const float* vp         = (const float*)d_in[2];
    const int*   faces      = (const int*)d_in[3];
    const float* rot_qs     = (const float*)d_in[4];
    const float* log_scales = (const float*)d_in[5];
    const float* colors     = (const float*)d_in[6];
    const float* log_opac   = (const float*)d_in[7];
    float* out    = (float*)d_out;
    float* params = (float*)d_ws;   // 32 KB used

    prep_sort_kernel<<<1, F_CNT, 0, stream>>>(vp, faces, rot_qs, log_scales,
                                              colors, log_opac, params, out);
    render_kernel<<<(HW / 2) / HALF_PX, 512, 0, stream>>>(params, img, mask, out);
}